// Round 6
// baseline (327.724 us; speedup 1.0000x reference)
//
#include <hip/hip_runtime.h>

typedef __bf16 bf16x8 __attribute__((ext_vector_type(8)));
typedef float floatx4 __attribute__((ext_vector_type(4)));
typedef unsigned short ushort_t;
typedef ushort_t ushortx4 __attribute__((ext_vector_type(4)));
typedef float floatx4v __attribute__((ext_vector_type(4)));

typedef __attribute__((address_space(1))) void gvoid;
typedef __attribute__((address_space(3))) void svoid;

#define MFMA16(a, b, c) __builtin_amdgcn_mfma_f32_16x16x32_bf16(a, b, c, 0, 0, 0)

__device__ __forceinline__ ushort_t f2bf(float f) {
  unsigned u = __builtin_bit_cast(unsigned, f);
  u += 0x7fffu + ((u >> 16) & 1u);
  return (ushort_t)(u >> 16);
}

__device__ __forceinline__ ushort_t bftrunc(float f) {
  return (ushort_t)(__builtin_bit_cast(unsigned, f) >> 16);
}

__device__ __forceinline__ void gld16(const ushort_t* g, ushort_t* l) {
  __builtin_amdgcn_global_load_lds((gvoid*)(g), (svoid*)(l), 16, 0, 0);
}

// ---------------------------------------------------------------- cast x -> bf16
__global__ __launch_bounds__(256) void k_cast_x(const floatx4v* __restrict__ in,
                                                ushortx4* __restrict__ out) {
  int i = blockIdx.x * 256 + threadIdx.x;
  floatx4v v = in[i];
  ushortx4 o;
  o[0] = f2bf(v[0]); o[1] = f2bf(v[1]); o[2] = f2bf(v[2]); o[3] = f2bf(v[3]);
  out[i] = o;
}

// ---------------------------------------------------------------- all 4 weights: transpose+cast, one launch
__global__ __launch_bounds__(256) void k_prep_w(const float* __restrict__ Wq,
                                                const float* __restrict__ Wk,
                                                const float* __restrict__ Wv,
                                                const float* __restrict__ Wo,
                                                ushort_t* __restrict__ WqkvT,
                                                ushort_t* __restrict__ WoT) {
  __shared__ float tile[64][65];
  const int bx = blockIdx.x;
  const float* in;
  ushort_t* out;
  int N, cx;
  if (bx < 32)      { in = Wq; out = WqkvT;              N = 2048; cx = bx; }
  else if (bx < 40) { in = Wk; out = WqkvT + 2048*2048;  N = 512;  cx = bx - 32; }
  else if (bx < 48) { in = Wv; out = WqkvT + 2560*2048;  N = 512;  cx = bx - 40; }
  else              { in = Wo; out = WoT;                N = 2048; cx = bx - 48; }
  const int c0 = cx * 64;
  const int k0 = blockIdx.y * 64;
  const int tx = threadIdx.x & 63;
  const int ty = threadIdx.x >> 6;
#pragma unroll
  for (int i = 0; i < 16; i++) {
    int row = i * 4 + ty;
    tile[tx][row] = in[(k0 + row) * N + c0 + tx];
  }
  __syncthreads();
#pragma unroll
  for (int i = 0; i < 16; i++) {
    int nr = i * 4 + ty;
    out[(c0 + nr) * 2048 + k0 + tx] = f2bf(tile[nr][tx]);
  }
}

// ---------------------------------------------------------------- fused QKV GEMM + RoPE epilogue
__global__ __launch_bounds__(256) void k_gemm_qkv(const ushort_t* __restrict__ A,
                                                  const ushort_t* __restrict__ Bt,
                                                  ushort_t* __restrict__ Qh,
                                                  ushort_t* __restrict__ Kh,
                                                  ushort_t* __restrict__ Vt) {
  __shared__ __align__(16) ushort_t As[2][4096];
  __shared__ __align__(16) ushort_t Bs[2][4096];
  const int t = threadIdx.x;
  const int w = t >> 6;
  const int lane = t & 63;
  const int r = lane & 15;
  const int q = lane >> 4;
  const int m0 = blockIdx.y * 128;
  const int n0 = blockIdx.x * 128;

  const int srow = t >> 2;
  const int gc = (t & 3) ^ ((t >> 3) & 3);          // swizzled global chunk
  const int a_g0 = (m0 + srow) * 2048 + gc * 8;
  const int b_g0 = (n0 + srow) * 2048 + gc * 8;

  const int pos8 = (q ^ ((r >> 1) & 3)) * 8;        // swizzled read position
  const int a_off = (w * 32 + r) * 32 + pos8;
  const int b_off = r * 32 + pos8;

  const floatx4 fz = {0.f, 0.f, 0.f, 0.f};
  floatx4 acc[2][8];
#pragma unroll
  for (int i = 0; i < 2; i++)
#pragma unroll
    for (int jj = 0; jj < 8; jj++) acc[i][jj] = fz;

  gld16(A + a_g0, As[0] + t * 8);
  gld16(A + a_g0 + 64 * 2048, As[0] + 2048 + t * 8);
  gld16(Bt + b_g0, Bs[0] + t * 8);
  gld16(Bt + b_g0 + 64 * 2048, Bs[0] + 2048 + t * 8);

  for (int it = 0; it < 64; it++) {
    const int c = it & 1;
    __syncthreads();
    if (it < 63) {
      const int kt = (it + 1) * 32;
      gld16(A + a_g0 + kt, As[1 - c] + t * 8);
      gld16(A + a_g0 + 64 * 2048 + kt, As[1 - c] + 2048 + t * 8);
      gld16(Bt + b_g0 + kt, Bs[1 - c] + t * 8);
      gld16(Bt + b_g0 + 64 * 2048 + kt, Bs[1 - c] + 2048 + t * 8);
    }
    bf16x8 af0 = *(const bf16x8*)(As[c] + a_off);
    bf16x8 af1 = *(const bf16x8*)(As[c] + a_off + 512);
    bf16x8 bfv[8];
#pragma unroll
    for (int ni = 0; ni < 8; ni++) bfv[ni] = *(const bf16x8*)(Bs[c] + b_off + ni * 512);
#pragma unroll
    for (int ni = 0; ni < 8; ni++) {
      acc[0][ni] = MFMA16(af0, bfv[ni], acc[0][ni]);
      acc[1][ni] = MFMA16(af1, bfv[ni], acc[1][ni]);
    }
  }

  const int bb = m0 >> 11;                 // batch index (tile never spans b)
  const int trow0 = (m0 & 2047) + w * 32;  // token base for this wave

  if (n0 < 2560) {
    const bool isQ = (n0 < 2048);
    const float scale = isQ ? 0.08838834764831845f : 1.0f;
    ushort_t* dst = isQ ? (Qh + ((bb * 16 + (n0 >> 7)) * 2048) * 128)
                        : (Kh + ((bb * 4 + ((n0 - 2048) >> 7)) * 2048) * 128);
#pragma unroll
    for (int mi = 0; mi < 2; mi++) {
#pragma unroll
      for (int ni = 0; ni < 4; ni++) {
        const int d = ni * 16 + r;
        const float invf = __expf(-0.14391156643f * (float)d);  // 10000^(-d/64)
#pragma unroll
        for (int reg = 0; reg < 4; reg++) {
          const int tt = trow0 + mi * 16 + q * 4 + reg;
          float sn, cs;
          __sincosf((float)tt * invf, &sn, &cs);
          const float lo = acc[mi][ni][reg];
          const float hi = acc[mi][ni + 4][reg];
          dst[tt * 128 + d] = f2bf((lo * cs - hi * sn) * scale);
          dst[tt * 128 + d + 64] = f2bf((hi * cs + lo * sn) * scale);
        }
      }
    }
  } else {
    ushort_t* dst = Vt + ((bb * 4 + ((n0 - 2560) >> 7)) * 128) * 2048;
#pragma unroll
    for (int mi = 0; mi < 2; mi++) {
#pragma unroll
      for (int ni = 0; ni < 8; ni++) {
        const int d = ni * 16 + r;
        const int t0 = trow0 + mi * 16 + q * 4;
        ushortx4 pk;
#pragma unroll
        for (int reg = 0; reg < 4; reg++) pk[reg] = f2bf(acc[mi][ni][reg]);
        *(ushortx4*)(dst + d * 2048 + t0) = pk;
      }
    }
  }
}

// ---------------------------------------------------------------- flash helpers (fixed-max softmax)
// mask (optional) + P = exp(s - 8) + lane-local row-sum for one tile
__device__ __forceinline__ void softmax_tile(floatx4* s, float* lsum,
                                             int w, int r, int q, bool diag) {
  if (diag) {
#pragma unroll
    for (int ni = 0; ni < 4; ni++)
#pragma unroll
      for (int reg = 0; reg < 4; reg++) {
        const int row_l = w * 16 + q * 4 + reg;
        const int col_l = ni * 16 + r;
        if (col_l > row_l) s[ni][reg] = -1e30f;
      }
  }
#pragma unroll
  for (int ni = 0; ni < 4; ni++)
#pragma unroll
    for (int reg = 0; reg < 4; reg++)
      s[ni][reg] = __expf(s[ni][reg] - 8.0f);  // masked -> 0
#pragma unroll
  for (int reg = 0; reg < 4; reg++)
    lsum[reg] += (s[0][reg] + s[1][reg]) + (s[2][reg] + s[3][reg]);
}

// P (bf16, truncation-pack) -> per-wave LDS scratch, A-operand swizzled layout
__device__ __forceinline__ void p_store(const floatx4* s, ushort_t* Pw, int r, int q) {
#pragma unroll
  for (int ni = 0; ni < 4; ni++)
#pragma unroll
    for (int reg = 0; reg < 4; reg++) {
      const int row_l = q * 4 + reg;
      const int col = ni * 16 + r;
      Pw[row_l * 64 + ((col >> 3) ^ (row_l & 7)) * 8 + (col & 7)] = bftrunc(s[ni][reg]);
    }
}

// ---------------------------------------------------------------- flash attention (causal, GQA, folded, fixed-max)
// Block owns Q-tile pair (p, 31-p): 33 tile-iterations, uniform makespan.
// Dual phase (j <= p): K/V fragments read ONCE, feed both tiles' MFMAs
// (LDS-pipe is the measured bottleneck). K/V dbuf; Q frags in regs; P aliases Kc.
__global__ __launch_bounds__(256) void k_flash(const ushort_t* __restrict__ Qh,
                                               const ushort_t* __restrict__ Kh,
                                               const ushort_t* __restrict__ Vt,
                                               ushort_t* __restrict__ attn) {
  __shared__ __align__(16) ushort_t smem[32768];  // K dbuf [0,16K), V dbuf [16K,32K)

  const int t = threadIdx.x;
  const int w = t >> 6;
  const int lane = t & 63;
  const int r = lane & 15;
  const int q = lane >> 4;
  const int rx = r & 7;

  // remap: block i and i+256 share a CU; p + p' = 15 equalizes per-CU j-iters (49)
  const int kk = blockIdx.x & 255;
  const int hi2 = blockIdx.x >> 8;
  const int bh = kk >> 3;
  const int ss = kk & 7;
  const int p = hi2 ? (15 - ss) : ss;

  const int b = bh >> 4;
  const int h = bh & 15;
  const int hkv = h >> 2;

  const int tA = p;         // small tile: kv tiles [0, p]
  const int tB = 31 - p;    // large tile: kv tiles [0, 31-p]
  const int jA = p + 1;
  const int jmax = 32 - p;

  const ushort_t* Qg = Qh + (bh * 2048) * 128;
  const ushort_t* Kg = Kh + ((b * 4 + hkv) * 2048) * 128;
  const ushort_t* Vg = Vt + ((b * 4 + hkv) * 128) * 2048;

  // ---- stage both Q tiles through LDS (K dbuf region), hoist frags to regs
  {
    const int qrow = t >> 4;
    const int gcq = (t & 15) ^ (qrow & 7);
#pragma unroll
    for (int i = 0; i < 4; i++)
      gld16(Qg + (tA * 64 + i * 16 + qrow) * 128 + gcq * 8, smem + i * 2048 + t * 8);
#pragma unroll
    for (int i = 0; i < 4; i++)
      gld16(Qg + (tB * 64 + i * 16 + qrow) * 128 + gcq * 8, smem + 8192 + i * 2048 + t * 8);
  }
  __syncthreads();
  bf16x8 aqA[4], aqB[4];
#pragma unroll
  for (int ks = 0; ks < 4; ks++) {
    const int pp = ((ks * 4 + q) ^ rx) * 8;
    aqA[ks] = *(const bf16x8*)(smem + (w * 16 + r) * 128 + pp);
    aqB[ks] = *(const bf16x8*)(smem + 8192 + (w * 16 + r) * 128 + pp);
  }
  __syncthreads();  // Q reads done before K0/V0 overwrite the region

  const int krow = t >> 4;
  const int gck = (t & 15) ^ (krow & 7);
  const int vrow = t >> 3;
  const int gcv = (t & 7) ^ (vrow & 7);

  // issue K0/V0 into buf 0
#pragma unroll
  for (int i = 0; i < 4; i++)
    gld16(Kg + (i * 16 + krow) * 128 + gck * 8, smem + i * 2048 + t * 8);
#pragma unroll
  for (int i = 0; i < 4; i++)
    gld16(Vg + (i * 32 + vrow) * 2048 + gcv * 8, smem + 16384 + i * 2048 + t * 8);

  const floatx4 fz = {0.f, 0.f, 0.f, 0.f};
  floatx4 accA[8], accB[8];
#pragma unroll
  for (int i = 0; i < 8; i++) { accA[i] = fz; accB[i] = fz; }
  float lA[4], lB[4];
#pragma unroll
  for (int i = 0; i < 4; i++) { lA[i] = 0.f; lB[i] = 0.f; }

  floatx4 sA[4], sB[4];

  for (int j = 0; j < jmax; j++) {
    const int c = j & 1;
    ushort_t* Kc = smem + c * 8192;
    ushort_t* Vc = smem + 16384 + c * 8192;
    __syncthreads();  // b1: buf 1-c free (prev PV + P reads done)
    if (j + 1 < jmax) {
      ushort_t* Kn = smem + (1 - c) * 8192;
      ushort_t* Vn = smem + 16384 + (1 - c) * 8192;
#pragma unroll
      for (int i = 0; i < 4; i++)
        gld16(Kg + ((j + 1) * 64 + i * 16 + krow) * 128 + gck * 8, Kn + i * 2048 + t * 8);
#pragma unroll
      for (int i = 0; i < 4; i++)
        gld16(Vg + (i * 32 + vrow) * 2048 + (j + 1) * 64 + gcv * 8, Vn + i * 2048 + t * 8);
    }

    if (j < jA) {
      // ---- dual phase: shared K reads feed both tiles
#pragma unroll
      for (int ni = 0; ni < 4; ni++) { sA[ni] = fz; sB[ni] = fz; }
#pragma unroll
      for (int ks = 0; ks < 4; ks++) {
        const int pp = ((ks * 4 + q) ^ rx) * 8;
#pragma unroll
        for (int ni = 0; ni < 4; ni++) {
          bf16x8 bk = *(const bf16x8*)(Kc + (ni * 16 + r) * 128 + pp);
          sB[ni] = MFMA16(aqB[ks], bk, sB[ni]);
          sA[ni] = MFMA16(aqA[ks], bk, sA[ni]);
        }
      }
      softmax_tile(sB, lB, w, r, q, j == jmax - 1);
      softmax_tile(sA, lA, w, r, q, j == p);
      __syncthreads();  // b2: all QK reads of Kc done; drains j+1 prefetch
      p_store(sB, Kc + w * 1024, r, q);
      p_store(sA, Kc + 4096 + w * 1024, r, q);
#pragma unroll
      for (int ks = 0; ks < 2; ks++) {
        const int pp = ((ks * 4 + q) ^ rx) * 8;
        bf16x8 apB = *(const bf16x8*)(Kc + w * 1024 + r * 64 + pp);
        bf16x8 apA = *(const bf16x8*)(Kc + 4096 + w * 1024 + r * 64 + pp);
#pragma unroll
        for (int nd = 0; nd < 8; nd++) {
          bf16x8 bv = *(const bf16x8*)(Vc + (nd * 16 + r) * 64 + pp);
          accB[nd] = MFMA16(apB, bv, accB[nd]);
          accA[nd] = MFMA16(apA, bv, accA[nd]);
        }
      }
    } else {
      // ---- single phase: only tile B
#pragma unroll
      for (int ni = 0; ni < 4; ni++) sB[ni] = fz;
#pragma unroll
      for (int ks = 0; ks < 4; ks++) {
        const int pp = ((ks * 4 + q) ^ rx) * 8;
#pragma unroll
        for (int ni = 0; ni < 4; ni++) {
          bf16x8 bk = *(const bf16x8*)(Kc + (ni * 16 + r) * 128 + pp);
          sB[ni] = MFMA16(aqB[ks], bk, sB[ni]);
        }
      }
      softmax_tile(sB, lB, w, r, q, j == jmax - 1);
      __syncthreads();  // b2
      p_store(sB, Kc + w * 1024, r, q);
#pragma unroll
      for (int ks = 0; ks < 2; ks++) {
        const int pp = ((ks * 4 + q) ^ rx) * 8;
        bf16x8 apB = *(const bf16x8*)(Kc + w * 1024 + r * 64 + pp);
#pragma unroll
        for (int nd = 0; nd < 8; nd++) {
          bf16x8 bv = *(const bf16x8*)(Vc + (nd * 16 + r) * 64 + pp);
          accB[nd] = MFMA16(apB, bv, accB[nd]);
        }
      }
    }
  }

  // final row-sum reduction (once) + epilogue
#pragma unroll
  for (int reg = 0; reg < 4; reg++) {
#pragma unroll
    for (int d = 1; d < 16; d <<= 1) {
      lA[reg] += __shfl_xor(lA[reg], d);
      lB[reg] += __shfl_xor(lB[reg], d);
    }
  }
  ushort_t* dstA = attn + (b * 2048 + tA * 64) * 2048 + h * 128;
  ushort_t* dstB = attn + (b * 2048 + tB * 64) * 2048 + h * 128;
#pragma unroll
  for (int reg = 0; reg < 4; reg++) {
    const int row_l = w * 16 + q * 4 + reg;
    const float invA = 1.0f / lA[reg];
    const float invB = 1.0f / lB[reg];
#pragma unroll
    for (int nd = 0; nd < 8; nd++) {
      dstA[row_l * 2048 + nd * 16 + r] = f2bf(accA[nd][reg] * invA);
      dstB[row_l * 2048 + nd * 16 + r] = f2bf(accB[nd][reg] * invB);
    }
  }
}

// ---------------------------------------------------------------- output projection GEMM (dbuf, 1 barrier/step)
__global__ __launch_bounds__(256) void k_gemm_out(const ushort_t* __restrict__ A,
                                                  const ushort_t* __restrict__ Bt,
                                                  float* __restrict__ out) {
  __shared__ __align__(16) ushort_t As[2][4096];
  __shared__ __align__(16) ushort_t Bs[2][4096];
  const int t = threadIdx.x;
  const int w = t >> 6;
  const int lane = t & 63;
  const int r = lane & 15;
  const int q = lane >> 4;
  const int m0 = blockIdx.y * 128;
  const int n0 = blockIdx.x * 128;

  const int srow = t >> 2;
  const int gc = (t & 3) ^ ((t >> 3) & 3);
  const int a_g0 = (m0 + srow) * 2048 + gc * 8;
  const int b_g0 = (n0 + srow) * 2048 + gc * 8;

  const int pos8 = (q ^ ((r >> 1) & 3)) * 8;
  const int a_off = (w * 32 + r) * 32 + pos8;
  const int b_off = r * 32 + pos8;

  const floatx4 fz = {0.f, 0.f, 0.f, 0.f};
  floatx4 acc[2][8];
#pragma unroll
  for (int i = 0; i < 2; i++)
#pragma unroll
    for (int jj = 0; jj < 8; jj++) acc[i][jj] = fz;

  gld16(A + a_g0, As[0] + t * 8);
  gld16(A + a_g0 + 64 * 2048, As[0] + 2048 + t * 8);
  gld16(Bt + b_g0, Bs[0] + t * 8);
  gld16(Bt + b_g0 + 64 * 2048, Bs[0] + 2048 + t * 8);

  for (int it = 0; it < 64; it++) {
    const int c = it & 1;
    __syncthreads();
    if (it < 63) {
      const int kt = (it + 1) * 32;
      gld16(A + a_g0 + kt, As[1 - c] + t * 8);
      gld16(A + a_g0 + 64 * 2048 + kt, As[1 - c] + 2048 + t * 8);
      gld16(Bt + b_g0 + kt, Bs[1 - c] + t * 8);
      gld16(Bt + b_g0 + 64 * 2048 + kt, Bs[1 - c] + 2048 + t * 8);
    }
    bf16x8 af0 = *(const bf16x8*)(As[c] + a_off);
    bf16x8 af1 = *(const bf16x8*)(As[c] + a_off + 512);
    bf16x8 bfv[8];
#pragma unroll
    for (int ni = 0; ni < 8; ni++) bfv[ni] = *(const bf16x8*)(Bs[c] + b_off + ni * 512);
#pragma unroll
    for (int ni = 0; ni < 8; ni++) {
      acc[0][ni] = MFMA16(af0, bfv[ni], acc[0][ni]);
      acc[1][ni] = MFMA16(af1, bfv[ni], acc[1][ni]);
    }
  }

#pragma unroll
  for (int mi = 0; mi < 2; mi++)
#pragma unroll
    for (int ni = 0; ni < 8; ni++)
#pragma unroll
      for (int reg = 0; reg < 4; reg++)
        out[(m0 + w * 32 + mi * 16 + q * 4 + reg) * 2048 + n0 + ni * 16 + r] =
            acc[mi][ni][reg];
}

// ---------------------------------------------------------------- launch
extern "C" void kernel_launch(void* const* d_in, const int* in_sizes, int n_in,
                              void* d_out, int out_size, void* d_ws, size_t ws_size,
                              hipStream_t stream) {
  (void)in_sizes; (void)n_in; (void)out_size; (void)ws_size;
  const float* x  = (const float*)d_in[0];
  const float* Wq = (const float*)d_in[1];
  const float* Wk = (const float*)d_in[2];
  const float* Wv = (const float*)d_in[3];
  const float* Wo = (const float*)d_in[4];
  float* out = (float*)d_out;

  char* ws = (char*)d_ws;
  ushort_t* x_bf   = (ushort_t*)(ws);               // 4096x2048        16,777,216 B
  ushort_t* WqkvT  = (ushort_t*)(ws + 16777216);    // 3072x2048        12,582,912 B
  ushort_t* WoT    = (ushort_t*)(ws + 29360128);    // 2048x2048         8,388,608 B
  ushort_t* Qh     = (ushort_t*)(ws + 37748736);    // (B,16,2048,128)  16,777,216 B
  ushort_t* Kh     = (ushort_t*)(ws + 54525952);    // (B,4,2048,128)    4,194,304 B
  ushort_t* Vt     = (ushort_t*)(ws + 58720256);    // (B,4,128,2048)    4,194,304 B
  ushort_t* attn   = (ushort_t*)(ws + 62914560);    // 4096x2048        16,777,216 B

  k_cast_x<<<8192, 256, 0, stream>>>((const floatx4v*)x, (ushortx4*)x_bf);
  k_prep_w<<<dim3(80, 32), 256, 0, stream>>>(Wq, Wk, Wv, Wo, WqkvT, WoT);
  k_gemm_qkv<<<dim3(24, 32), 256, 0, stream>>>(x_bf, WqkvT, Qh, Kh, Vt);
  k_flash<<<512, 256, 0, stream>>>(Qh, Kh, Vt, attn);
  k_gemm_out<<<dim3(16, 32), 256, 0, stream>>>(attn, WoT, out);
}

// Round 7
// 313.473 us; speedup vs baseline: 1.0455x; 1.0455x over previous
//
#include <hip/hip_runtime.h>

typedef __bf16 bf16x8 __attribute__((ext_vector_type(8)));
typedef float floatx4 __attribute__((ext_vector_type(4)));
typedef unsigned short ushort_t;
typedef ushort_t ushortx4 __attribute__((ext_vector_type(4)));
typedef float floatx4v __attribute__((ext_vector_type(4)));

typedef __attribute__((address_space(1))) void gvoid;
typedef __attribute__((address_space(3))) void svoid;

#define MFMA16(a, b, c) __builtin_amdgcn_mfma_f32_16x16x32_bf16(a, b, c, 0, 0, 0)

__device__ __forceinline__ ushort_t f2bf(float f) {
  unsigned u = __builtin_bit_cast(unsigned, f);
  u += 0x7fffu + ((u >> 16) & 1u);
  return (ushort_t)(u >> 16);
}

__device__ __forceinline__ void gld16(const ushort_t* g, ushort_t* l) {
  __builtin_amdgcn_global_load_lds((gvoid*)(g), (svoid*)(l), 16, 0, 0);
}

// ---------------------------------------------------------------- prologue: cast x + transpose/cast all weights (one launch)
__global__ __launch_bounds__(256) void k_prep(const floatx4v* __restrict__ xin,
                                              ushortx4* __restrict__ x_bf,
                                              const float* __restrict__ Wq,
                                              const float* __restrict__ Wk,
                                              const float* __restrict__ Wv,
                                              const float* __restrict__ Wo,
                                              ushort_t* __restrict__ WqkvT,
                                              ushort_t* __restrict__ WoT) {
  __shared__ float tile[64][65];
  if (blockIdx.x < 8192) {
    int i = blockIdx.x * 256 + threadIdx.x;
    floatx4v v = xin[i];
    ushortx4 o;
    o[0] = f2bf(v[0]); o[1] = f2bf(v[1]); o[2] = f2bf(v[2]); o[3] = f2bf(v[3]);
    x_bf[i] = o;
    return;
  }
  const int pb = blockIdx.x - 8192;   // 0..2559 = 80 x 32
  const int byy = pb / 80;
  const int bx = pb - byy * 80;
  const float* in;
  ushort_t* out;
  int N, cx;
  if (bx < 32)      { in = Wq; out = WqkvT;              N = 2048; cx = bx; }
  else if (bx < 40) { in = Wk; out = WqkvT + 2048*2048;  N = 512;  cx = bx - 32; }
  else if (bx < 48) { in = Wv; out = WqkvT + 2560*2048;  N = 512;  cx = bx - 40; }
  else              { in = Wo; out = WoT;                N = 2048; cx = bx - 48; }
  const int c0 = cx * 64;
  const int k0 = byy * 64;
  const int tx = threadIdx.x & 63;
  const int ty = threadIdx.x >> 6;
#pragma unroll
  for (int i = 0; i < 16; i++) {
    int row = i * 4 + ty;
    tile[tx][row] = in[(k0 + row) * N + c0 + tx];
  }
  __syncthreads();
#pragma unroll
  for (int i = 0; i < 16; i++) {
    int nr = i * 4 + ty;
    out[(c0 + nr) * 2048 + k0 + tx] = f2bf(tile[nr][tx]);
  }
}

// ---------------------------------------------------------------- fused QKV GEMM + RoPE epilogue
// grid 768 = exactly 3 blocks/CU; launch_bounds(…,3) guarantees co-residency.
__global__ __launch_bounds__(256, 3) void k_gemm_qkv(const ushort_t* __restrict__ A,
                                                     const ushort_t* __restrict__ Bt,
                                                     ushort_t* __restrict__ Qh,
                                                     ushort_t* __restrict__ Kh,
                                                     ushort_t* __restrict__ Vt) {
  __shared__ __align__(16) ushort_t As[2][4096];
  __shared__ __align__(16) ushort_t Bs[2][4096];
  const int t = threadIdx.x;
  const int w = t >> 6;
  const int lane = t & 63;
  const int r = lane & 15;
  const int q = lane >> 4;
  const int m0 = blockIdx.y * 128;
  const int n0 = blockIdx.x * 128;

  const int srow = t >> 2;
  const int gc = (t & 3) ^ ((t >> 3) & 3);          // swizzled global chunk
  const int a_g0 = (m0 + srow) * 2048 + gc * 8;
  const int b_g0 = (n0 + srow) * 2048 + gc * 8;

  const int pos8 = (q ^ ((r >> 1) & 3)) * 8;        // swizzled read position
  const int a_off = (w * 32 + r) * 32 + pos8;
  const int b_off = r * 32 + pos8;

  const floatx4 fz = {0.f, 0.f, 0.f, 0.f};
  floatx4 acc[2][8];
#pragma unroll
  for (int i = 0; i < 2; i++)
#pragma unroll
    for (int jj = 0; jj < 8; jj++) acc[i][jj] = fz;

  gld16(A + a_g0, As[0] + t * 8);
  gld16(A + a_g0 + 64 * 2048, As[0] + 2048 + t * 8);
  gld16(Bt + b_g0, Bs[0] + t * 8);
  gld16(Bt + b_g0 + 64 * 2048, Bs[0] + 2048 + t * 8);

  for (int it = 0; it < 64; it++) {
    const int c = it & 1;
    __syncthreads();
    if (it < 63) {
      const int kt = (it + 1) * 32;
      gld16(A + a_g0 + kt, As[1 - c] + t * 8);
      gld16(A + a_g0 + 64 * 2048 + kt, As[1 - c] + 2048 + t * 8);
      gld16(Bt + b_g0 + kt, Bs[1 - c] + t * 8);
      gld16(Bt + b_g0 + 64 * 2048 + kt, Bs[1 - c] + 2048 + t * 8);
    }
    bf16x8 af0 = *(const bf16x8*)(As[c] + a_off);
    bf16x8 af1 = *(const bf16x8*)(As[c] + a_off + 512);
    bf16x8 bfv[8];
#pragma unroll
    for (int ni = 0; ni < 8; ni++) bfv[ni] = *(const bf16x8*)(Bs[c] + b_off + ni * 512);
#pragma unroll
    for (int ni = 0; ni < 8; ni++) {
      acc[0][ni] = MFMA16(af0, bfv[ni], acc[0][ni]);
      acc[1][ni] = MFMA16(af1, bfv[ni], acc[1][ni]);
    }
  }

  const int bb = m0 >> 11;                 // batch index (tile never spans b)
  const int trow0 = (m0 & 2047) + w * 32;  // token base for this wave

  if (n0 < 2560) {
    const bool isQ = (n0 < 2048);
    const float scale = isQ ? 0.08838834764831845f : 1.0f;
    ushort_t* dst = isQ ? (Qh + ((bb * 16 + (n0 >> 7)) * 2048) * 128)
                        : (Kh + ((bb * 4 + ((n0 - 2048) >> 7)) * 2048) * 128);
#pragma unroll
    for (int mi = 0; mi < 2; mi++) {
#pragma unroll
      for (int ni = 0; ni < 4; ni++) {
        const int d = ni * 16 + r;
        const float invf = __expf(-0.14391156643f * (float)d);  // 10000^(-d/64)
#pragma unroll
        for (int reg = 0; reg < 4; reg++) {
          const int tt = trow0 + mi * 16 + q * 4 + reg;
          float sn, cs;
          __sincosf((float)tt * invf, &sn, &cs);
          const float lo = acc[mi][ni][reg];
          const float hi = acc[mi][ni + 4][reg];
          dst[tt * 128 + d] = f2bf((lo * cs - hi * sn) * scale);
          dst[tt * 128 + d + 64] = f2bf((hi * cs + lo * sn) * scale);
        }
      }
    }
  } else {
    ushort_t* dst = Vt + ((bb * 4 + ((n0 - 2560) >> 7)) * 128) * 2048;
#pragma unroll
    for (int mi = 0; mi < 2; mi++) {
#pragma unroll
      for (int ni = 0; ni < 8; ni++) {
        const int d = ni * 16 + r;
        const int t0 = trow0 + mi * 16 + q * 4;
        ushortx4 pk;
#pragma unroll
        for (int reg = 0; reg < 4; reg++) pk[reg] = f2bf(acc[mi][ni][reg]);
        *(ushortx4*)(dst + d * 2048 + t0) = pk;
      }
    }
  }
}

// ---------------------------------------------------------------- flash helpers (fixed-max softmax)  [R5 version]
__device__ __forceinline__ void attn_s(const bf16x8* aq, floatx4* s_acc,
                                       float* lsum, const ushort_t* Kc,
                                       int w, int r, int q, int rx, bool diag) {
  const floatx4 fz = {0.f, 0.f, 0.f, 0.f};
#pragma unroll
  for (int ni = 0; ni < 4; ni++) s_acc[ni] = fz;
#pragma unroll
  for (int ks = 0; ks < 4; ks++) {
    const int pp = ((ks * 4 + q) ^ rx) * 8;
#pragma unroll
    for (int ni = 0; ni < 4; ni++) {
      bf16x8 bk = *(const bf16x8*)(Kc + (ni * 16 + r) * 128 + pp);
      s_acc[ni] = MFMA16(aq[ks], bk, s_acc[ni]);
    }
  }
  if (diag) {
#pragma unroll
    for (int ni = 0; ni < 4; ni++)
#pragma unroll
      for (int reg = 0; reg < 4; reg++) {
        const int row_l = w * 16 + q * 4 + reg;
        const int col_l = ni * 16 + r;
        if (col_l > row_l) s_acc[ni][reg] = -1e30f;
      }
  }
#pragma unroll
  for (int ni = 0; ni < 4; ni++)
#pragma unroll
    for (int reg = 0; reg < 4; reg++)
      s_acc[ni][reg] = __expf(s_acc[ni][reg] - 8.0f);  // masked -> 0
#pragma unroll
  for (int reg = 0; reg < 4; reg++)
    lsum[reg] += (s_acc[0][reg] + s_acc[1][reg]) + (s_acc[2][reg] + s_acc[3][reg]);
}

__device__ __forceinline__ void attn_pv(const floatx4* s_acc, floatx4* acc_o,
                                        const ushort_t* Vc, ushort_t* Pw,
                                        int r, int q, int rx) {
#pragma unroll
  for (int ni = 0; ni < 4; ni++)
#pragma unroll
    for (int reg = 0; reg < 4; reg++) {
      const int row_l = q * 4 + reg;
      const int col = ni * 16 + r;
      Pw[row_l * 64 + ((col >> 3) ^ (row_l & 7)) * 8 + (col & 7)] =
          f2bf(s_acc[ni][reg]);
    }
#pragma unroll
  for (int ks = 0; ks < 2; ks++) {
    const int pp = ((ks * 4 + q) ^ rx) * 8;
    bf16x8 ap = *(const bf16x8*)(Pw + r * 64 + pp);
#pragma unroll
    for (int nd = 0; nd < 8; nd++) {
      bf16x8 bv = *(const bf16x8*)(Vc + (nd * 16 + r) * 64 + pp);
      acc_o[nd] = MFMA16(ap, bv, acc_o[nd]);
    }
  }
}

// ---------------------------------------------------------------- flash attention (causal, GQA, folded, fixed-max) [R5]
__global__ __launch_bounds__(256) void k_flash(const ushort_t* __restrict__ Qh,
                                               const ushort_t* __restrict__ Kh,
                                               const ushort_t* __restrict__ Vt,
                                               ushort_t* __restrict__ attn) {
  __shared__ __align__(16) ushort_t smem[32768];  // K dbuf [0,16K), V dbuf [16K,32K)

  const int t = threadIdx.x;
  const int w = t >> 6;
  const int lane = t & 63;
  const int r = lane & 15;
  const int q = lane >> 4;
  const int rx = r & 7;

  // remap: block i and i+256 share a CU; p + p' = 15 equalizes per-CU j-iters (49)
  const int kk = blockIdx.x & 255;
  const int hi2 = blockIdx.x >> 8;
  const int bh = kk >> 3;
  const int ss = kk & 7;
  const int p = hi2 ? (15 - ss) : ss;

  const int b = bh >> 4;
  const int h = bh & 15;
  const int hkv = h >> 2;

  const int tA = p;         // small tile: kv tiles [0, p]
  const int tB = 31 - p;    // large tile: kv tiles [0, 31-p]
  const int jA = p + 1;
  const int jmax = 32 - p;

  const ushort_t* Qg = Qh + (bh * 2048) * 128;
  const ushort_t* Kg = Kh + ((b * 4 + hkv) * 2048) * 128;
  const ushort_t* Vg = Vt + ((b * 4 + hkv) * 128) * 2048;

  // ---- stage both Q tiles through LDS (K dbuf region), hoist frags to regs
  {
    const int qrow = t >> 4;
    const int gcq = (t & 15) ^ (qrow & 7);
#pragma unroll
    for (int i = 0; i < 4; i++)
      gld16(Qg + (tA * 64 + i * 16 + qrow) * 128 + gcq * 8, smem + i * 2048 + t * 8);
#pragma unroll
    for (int i = 0; i < 4; i++)
      gld16(Qg + (tB * 64 + i * 16 + qrow) * 128 + gcq * 8, smem + 8192 + i * 2048 + t * 8);
  }
  __syncthreads();
  bf16x8 aqA[4], aqB[4];
#pragma unroll
  for (int ks = 0; ks < 4; ks++) {
    const int pp = ((ks * 4 + q) ^ rx) * 8;
    aqA[ks] = *(const bf16x8*)(smem + (w * 16 + r) * 128 + pp);
    aqB[ks] = *(const bf16x8*)(smem + 8192 + (w * 16 + r) * 128 + pp);
  }
  __syncthreads();  // Q reads done before K0/V0 overwrite the region

  const int krow = t >> 4;
  const int gck = (t & 15) ^ (krow & 7);
  const int vrow = t >> 3;
  const int gcv = (t & 7) ^ (vrow & 7);

  // issue K0/V0 into buf 0
#pragma unroll
  for (int i = 0; i < 4; i++)
    gld16(Kg + (i * 16 + krow) * 128 + gck * 8, smem + i * 2048 + t * 8);
#pragma unroll
  for (int i = 0; i < 4; i++)
    gld16(Vg + (i * 32 + vrow) * 2048 + gcv * 8, smem + 16384 + i * 2048 + t * 8);

  const floatx4 fz = {0.f, 0.f, 0.f, 0.f};
  floatx4 accA[8], accB[8];
#pragma unroll
  for (int i = 0; i < 8; i++) { accA[i] = fz; accB[i] = fz; }
  float lA[4], lB[4];
#pragma unroll
  for (int i = 0; i < 4; i++) { lA[i] = 0.f; lB[i] = 0.f; }

  floatx4 sA[4], sB[4];

  for (int j = 0; j < jmax; j++) {
    const int c = j & 1;
    ushort_t* Kc = smem + c * 8192;
    ushort_t* Vc = smem + 16384 + c * 8192;
    __syncthreads();  // b1: buf 1-c free (prev PV + P reads done)
    if (j + 1 < jmax) {
      ushort_t* Kn = smem + (1 - c) * 8192;
      ushort_t* Vn = smem + 16384 + (1 - c) * 8192;
#pragma unroll
      for (int i = 0; i < 4; i++)
        gld16(Kg + ((j + 1) * 64 + i * 16 + krow) * 128 + gck * 8, Kn + i * 2048 + t * 8);
#pragma unroll
      for (int i = 0; i < 4; i++)
        gld16(Vg + (i * 32 + vrow) * 2048 + (j + 1) * 64 + gcv * 8, Vn + i * 2048 + t * 8);
    }

    const bool actA = (j < jA);
    attn_s(aqB, sB, lB, Kc, w, r, q, rx, j == jmax - 1);
    if (actA) attn_s(aqA, sA, lA, Kc, w, r, q, rx, j == p);

    __syncthreads();  // b2: all QK reads of Kc done; drains j+1 prefetch
    attn_pv(sB, accB, Vc, Kc + w * 1024, r, q, rx);                   // P_B in Kc[0,4K)
    if (actA) attn_pv(sA, accA, Vc, Kc + 4096 + w * 1024, r, q, rx);  // P_A in Kc[4K,8K)
  }

  // final row-sum reduction (once) + epilogue
#pragma unroll
  for (int reg = 0; reg < 4; reg++) {
#pragma unroll
    for (int d = 1; d < 16; d <<= 1) {
      lA[reg] += __shfl_xor(lA[reg], d);
      lB[reg] += __shfl_xor(lB[reg], d);
    }
  }
  ushort_t* dstA = attn + (b * 2048 + tA * 64) * 2048 + h * 128;
  ushort_t* dstB = attn + (b * 2048 + tB * 64) * 2048 + h * 128;
#pragma unroll
  for (int reg = 0; reg < 4; reg++) {
    const int row_l = w * 16 + q * 4 + reg;
    const float invA = 1.0f / lA[reg];
    const float invB = 1.0f / lB[reg];
#pragma unroll
    for (int nd = 0; nd < 8; nd++) {
      dstA[row_l * 2048 + nd * 16 + r] = f2bf(accA[nd][reg] * invA);
      dstB[row_l * 2048 + nd * 16 + r] = f2bf(accB[nd][reg] * invB);
    }
  }
}

// ---------------------------------------------------------------- output projection GEMM (dbuf, 1 barrier/step)
__global__ __launch_bounds__(256) void k_gemm_out(const ushort_t* __restrict__ A,
                                                  const ushort_t* __restrict__ Bt,
                                                  float* __restrict__ out) {
  __shared__ __align__(16) ushort_t As[2][4096];
  __shared__ __align__(16) ushort_t Bs[2][4096];
  const int t = threadIdx.x;
  const int w = t >> 6;
  const int lane = t & 63;
  const int r = lane & 15;
  const int q = lane >> 4;
  const int m0 = blockIdx.y * 128;
  const int n0 = blockIdx.x * 128;

  const int srow = t >> 2;
  const int gc = (t & 3) ^ ((t >> 3) & 3);
  const int a_g0 = (m0 + srow) * 2048 + gc * 8;
  const int b_g0 = (n0 + srow) * 2048 + gc * 8;

  const int pos8 = (q ^ ((r >> 1) & 3)) * 8;
  const int a_off = (w * 32 + r) * 32 + pos8;
  const int b_off = r * 32 + pos8;

  const floatx4 fz = {0.f, 0.f, 0.f, 0.f};
  floatx4 acc[2][8];
#pragma unroll
  for (int i = 0; i < 2; i++)
#pragma unroll
    for (int jj = 0; jj < 8; jj++) acc[i][jj] = fz;

  gld16(A + a_g0, As[0] + t * 8);
  gld16(A + a_g0 + 64 * 2048, As[0] + 2048 + t * 8);
  gld16(Bt + b_g0, Bs[0] + t * 8);
  gld16(Bt + b_g0 + 64 * 2048, Bs[0] + 2048 + t * 8);

  for (int it = 0; it < 64; it++) {
    const int c = it & 1;
    __syncthreads();
    if (it < 63) {
      const int kt = (it + 1) * 32;
      gld16(A + a_g0 + kt, As[1 - c] + t * 8);
      gld16(A + a_g0 + 64 * 2048 + kt, As[1 - c] + 2048 + t * 8);
      gld16(Bt + b_g0 + kt, Bs[1 - c] + t * 8);
      gld16(Bt + b_g0 + 64 * 2048 + kt, Bs[1 - c] + 2048 + t * 8);
    }
    bf16x8 af0 = *(const bf16x8*)(As[c] + a_off);
    bf16x8 af1 = *(const bf16x8*)(As[c] + a_off + 512);
    bf16x8 bfv[8];
#pragma unroll
    for (int ni = 0; ni < 8; ni++) bfv[ni] = *(const bf16x8*)(Bs[c] + b_off + ni * 512);
#pragma unroll
    for (int ni = 0; ni < 8; ni++) {
      acc[0][ni] = MFMA16(af0, bfv[ni], acc[0][ni]);
      acc[1][ni] = MFMA16(af1, bfv[ni], acc[1][ni]);
    }
  }

#pragma unroll
  for (int mi = 0; mi < 2; mi++)
#pragma unroll
    for (int ni = 0; ni < 8; ni++)
#pragma unroll
      for (int reg = 0; reg < 4; reg++)
        out[(m0 + w * 32 + mi * 16 + q * 4 + reg) * 2048 + n0 + ni * 16 + r] =
            acc[mi][ni][reg];
}

// ---------------------------------------------------------------- launch
extern "C" void kernel_launch(void* const* d_in, const int* in_sizes, int n_in,
                              void* d_out, int out_size, void* d_ws, size_t ws_size,
                              hipStream_t stream) {
  (void)in_sizes; (void)n_in; (void)out_size; (void)ws_size;
  const float* x  = (const float*)d_in[0];
  const float* Wq = (const float*)d_in[1];
  const float* Wk = (const float*)d_in[2];
  const float* Wv = (const float*)d_in[3];
  const float* Wo = (const float*)d_in[4];
  float* out = (float*)d_out;

  char* ws = (char*)d_ws;
  ushort_t* x_bf   = (ushort_t*)(ws);               // 4096x2048        16,777,216 B
  ushort_t* WqkvT  = (ushort_t*)(ws + 16777216);    // 3072x2048        12,582,912 B
  ushort_t* WoT    = (ushort_t*)(ws + 29360128);    // 2048x2048         8,388,608 B
  ushort_t* Qh     = (ushort_t*)(ws + 37748736);    // (B,16,2048,128)  16,777,216 B
  ushort_t* Kh     = (ushort_t*)(ws + 54525952);    // (B,4,2048,128)    4,194,304 B
  ushort_t* Vt     = (ushort_t*)(ws + 58720256);    // (B,4,128,2048)    4,194,304 B
  ushort_t* attn   = (ushort_t*)(ws + 62914560);    // 4096x2048        16,777,216 B

  k_prep<<<8192 + 2560, 256, 0, stream>>>((const floatx4v*)x, (ushortx4*)x_bf,
                                          Wq, Wk, Wv, Wo, WqkvT, WoT);
  k_gemm_qkv<<<dim3(24, 32), 256, 0, stream>>>(x_bf, WqkvT, Qh, Kh, Vt);
  k_flash<<<512, 256, 0, stream>>>(Qh, Kh, Vt, attn);
  k_gemm_out<<<dim3(16, 32), 256, 0, stream>>>(attn, WoT, out);
}